// Round 5
// baseline (237.354 us; speedup 1.0000x reference)
//
#include <hip/hip_runtime.h>
#include <hip/hip_bf16.h>

#define B 32
#define T 512
#define U 1024
#define E 1024
#define DIN 256
#define N4 4096  // 4*U
#define KCH 288  // k5: k-rows per block
#define NST 9    // k5: sub-tiles of 32 rows

__device__ __forceinline__ float fast_tanh(float x) {
    float e = __expf(2.0f * x);
    return 1.0f - 2.0f / (e + 1.0f);
}
__device__ __forceinline__ float fast_sigmoid(float x) {
    return 1.0f / (1.0f + __expf(-x));
}

// ================= K1: qpart[kc][b][u] partials of h @ Wa_w =================
__global__ __launch_bounds__(256) void k1_query(const float* __restrict__ h,
                                                const float* __restrict__ Wa_w,
                                                float* __restrict__ qpart) {
    const int jc = blockIdx.x;   // 0..7
    const int kc = blockIdx.y;   // 0..31
    const int tid = threadIdx.x;
    const int k0 = kc * 32;
    __shared__ float hs[32][36];   // [k][b] transposed, padded
    #pragma unroll
    for (int i = 0; i < 4; ++i) {
        int flat = i * 256 + tid;        // 1024
        int kk = flat & 31, b = flat >> 5;
        hs[kk][b] = h[(size_t)b * U + k0 + kk];
    }
    __syncthreads();
    const int jg = tid & 31;
    const int bg = tid >> 5;             // 0..7 -> batches bg*4..+3
    const int ROWS = U / 4;              // float4 stride per k-row
    const float4* Wp = (const float4*)(Wa_w + (size_t)k0 * U + jc * 128) + jg;
    float4 a0{}, a1{}, a2{}, a3{};
    float4 w0 = Wp[0 * ROWS], w1 = Wp[1 * ROWS], w2 = Wp[2 * ROWS], w3 = Wp[3 * ROWS];
#define K1_FMA(W, R)                                                            \
    {                                                                           \
        float4 x4 = *(const float4*)&hs[(R)][bg * 4];                           \
        a0.x += x4.x * (W).x; a0.y += x4.x * (W).y; a0.z += x4.x * (W).z; a0.w += x4.x * (W).w; \
        a1.x += x4.y * (W).x; a1.y += x4.y * (W).y; a1.z += x4.y * (W).z; a1.w += x4.y * (W).w; \
        a2.x += x4.z * (W).x; a2.y += x4.z * (W).y; a2.z += x4.z * (W).z; a2.w += x4.z * (W).w; \
        a3.x += x4.w * (W).x; a3.y += x4.w * (W).y; a3.z += x4.w * (W).z; a3.w += x4.w * (W).w; \
    }
    #pragma unroll 1
    for (int r = 0; r <= 24; r += 4) {
        float4 n0 = Wp[(r + 4) * ROWS], n1 = Wp[(r + 5) * ROWS];
        float4 n2 = Wp[(r + 6) * ROWS], n3 = Wp[(r + 7) * ROWS];
        K1_FMA(w0, r + 0); K1_FMA(w1, r + 1); K1_FMA(w2, r + 2); K1_FMA(w3, r + 3);
        w0 = n0; w1 = n1; w2 = n2; w3 = n3;
        if (r == 24) break;  // rows 28..31 remain in w0..w3
    }
    K1_FMA(w0, 28); K1_FMA(w1, 29); K1_FMA(w2, 30); K1_FMA(w3, 31);
#undef K1_FMA
    float* q = qpart + ((size_t)(kc * 32 + bg * 4)) * U + jc * 128 + jg * 4;
    *(float4*)(q + 0 * U) = a0;
    *(float4*)(q + 1 * U) = a1;
    *(float4*)(q + 2 * U) = a2;
    *(float4*)(q + 3 * U) = a3;
}

// ================= K1b: query = sum(32 qparts) + Wa_b =================
__global__ __launch_bounds__(256) void k1b_qreduce(const float* __restrict__ qpart,
                                                   const float* __restrict__ Wa_b,
                                                   float* __restrict__ query) {
    int i = blockIdx.x * 256 + threadIdx.x;  // 32768
    const float* p = qpart + i;
    float s = Wa_b[i & 1023];
    #pragma unroll
    for (int g = 0; g < 8; ++g) {
        float b0 = p[(size_t)(4 * g + 0) * 32768];
        float b1 = p[(size_t)(4 * g + 1) * 32768];
        float b2 = p[(size_t)(4 * g + 2) * 32768];
        float b3 = p[(size_t)(4 * g + 3) * 32768];
        s += b0 + b1 + b2 + b3;
    }
    query[i] = s;
}

// ================= K2: logits =================
__global__ __launch_bounds__(256) void k2_logits(const float* __restrict__ query,
                                                 const float* __restrict__ enc,
                                                 const float* __restrict__ va_w,
                                                 const float* __restrict__ va_b,
                                                 float* __restrict__ logits) {
    int gw = blockIdx.x * 4 + (threadIdx.x >> 6);
    int lane = threadIdx.x & 63;
    int b = gw >> 9, t = gw & 511;
    const float4* e4 = (const float4*)(enc + ((size_t)(b * T + t)) * U);
    const float4* q4 = (const float4*)(query + (size_t)b * U);
    const float4* v4 = (const float4*)va_w;
    float4 e[4], q[4], v[4];
    #pragma unroll
    for (int i = 0; i < 4; ++i) {
        int idx = i * 64 + lane;
        e[i] = e4[idx]; q[i] = q4[idx]; v[i] = v4[idx];
    }
    float acc = 0.f;
    #pragma unroll
    for (int i = 0; i < 4; ++i) {
        acc += fast_tanh(e[i].x + q[i].x) * v[i].x;
        acc += fast_tanh(e[i].y + q[i].y) * v[i].y;
        acc += fast_tanh(e[i].z + q[i].z) * v[i].z;
        acc += fast_tanh(e[i].w + q[i].w) * v[i].w;
    }
    #pragma unroll
    for (int off = 32; off > 0; off >>= 1) acc += __shfl_xor(acc, off);
    if (lane == 0) logits[b * T + t] = acc + va_b[0];
}

// ================= K3: softmax =================
__global__ __launch_bounds__(256) void k3_softmax(const float* __restrict__ logits,
                                                  float* __restrict__ attn) {
    int b = blockIdx.x, tid = threadIdx.x, lane = tid & 63, w = tid >> 6;
    float l0 = logits[b * T + tid], l1 = logits[b * T + 256 + tid];
    float m = fmaxf(l0, l1);
    #pragma unroll
    for (int off = 32; off > 0; off >>= 1) m = fmaxf(m, __shfl_xor(m, off));
    __shared__ float sm[4], ss[4];
    if (lane == 0) sm[w] = m;
    __syncthreads();
    float M = fmaxf(fmaxf(sm[0], sm[1]), fmaxf(sm[2], sm[3]));
    float e0 = __expf(l0 - M), e1 = __expf(l1 - M);
    float s = e0 + e1;
    #pragma unroll
    for (int off = 32; off > 0; off >>= 1) s += __shfl_xor(s, off);
    if (lane == 0) ss[w] = s;
    __syncthreads();
    float inv = 1.0f / (ss[0] + ss[1] + ss[2] + ss[3]);
    attn[b * T + tid] = e0 * inv;
    attn[b * T + 256 + tid] = e1 * inv;
}

// ================= K4: ctxpart[slice][b][e] =================
__global__ __launch_bounds__(256) void k4_ctx(const float* __restrict__ attn,
                                              const float* __restrict__ speech,
                                              float* __restrict__ ctxpart) {
    int bid = blockIdx.x;
    int eh = bid & 1, tc = (bid >> 1) & 15, b = bid >> 5;
    int t0 = tc * 32;
    __shared__ float sat[32];
    if (threadIdx.x < 32) sat[threadIdx.x] = attn[b * T + t0 + threadIdx.x];
    __syncthreads();
    int eg = threadIdx.x & 127;
    int ts = threadIdx.x >> 7;           // 0/1 sub-stream
    int e = eh * 512 + eg * 4;
    const int S = E / 4;
    const float4* sp = (const float4*)(speech + ((size_t)(b * T + t0 + ts * 16)) * E + e);
    float4 acc{};
    float4 p0 = sp[0 * S], p1 = sp[1 * S], p2 = sp[2 * S], p3 = sp[3 * S];
    const float* a = &sat[ts * 16];
    #pragma unroll 1
    for (int tt = 0; tt <= 8; tt += 4) {
        float4 n0 = sp[(size_t)(tt + 4) * S], n1 = sp[(size_t)(tt + 5) * S];
        float4 n2 = sp[(size_t)(tt + 6) * S], n3 = sp[(size_t)(tt + 7) * S];
        float c0 = a[tt + 0], c1 = a[tt + 1], c2 = a[tt + 2], c3 = a[tt + 3];
        acc.x += c0 * p0.x; acc.y += c0 * p0.y; acc.z += c0 * p0.z; acc.w += c0 * p0.w;
        acc.x += c1 * p1.x; acc.y += c1 * p1.y; acc.z += c1 * p1.z; acc.w += c1 * p1.w;
        acc.x += c2 * p2.x; acc.y += c2 * p2.y; acc.z += c2 * p2.z; acc.w += c2 * p2.w;
        acc.x += c3 * p3.x; acc.y += c3 * p3.y; acc.z += c3 * p3.z; acc.w += c3 * p3.w;
        p0 = n0; p1 = n1; p2 = n2; p3 = n3;
        if (tt == 8) break;  // rows 12..15 in p0..p3
    }
    {
        float c0 = a[12], c1 = a[13], c2 = a[14], c3 = a[15];
        acc.x += c0 * p0.x; acc.y += c0 * p0.y; acc.z += c0 * p0.z; acc.w += c0 * p0.w;
        acc.x += c1 * p1.x; acc.y += c1 * p1.y; acc.z += c1 * p1.z; acc.w += c1 * p1.w;
        acc.x += c2 * p2.x; acc.y += c2 * p2.y; acc.z += c2 * p2.z; acc.w += c2 * p2.w;
        acc.x += c3 * p3.x; acc.y += c3 * p3.y; acc.z += c3 * p3.z; acc.w += c3 * p3.w;
    }
    int slice = tc * 2 + ts;             // 0..31
    *(float4*)(ctxpart + ((size_t)(slice * 32 + b)) * E + e) = acc;
}

// ================= K4b: context = sum(32 ctxparts) =================
__global__ __launch_bounds__(256) void k4b_ctxreduce(const float* __restrict__ ctxpart,
                                                     float* __restrict__ context) {
    int i = blockIdx.x * 256 + threadIdx.x;  // 32768
    const float* p = ctxpart + i;
    float s = 0.f;
    #pragma unroll
    for (int g = 0; g < 8; ++g) {
        float b0 = p[(size_t)(4 * g + 0) * 32768];
        float b1 = p[(size_t)(4 * g + 1) * 32768];
        float b2 = p[(size_t)(4 * g + 2) * 32768];
        float b3 = p[(size_t)(4 * g + 3) * 32768];
        s += b0 + b1 + b2 + b3;
    }
    context[i] = s;
}

// ================= K5: zpart, 256 blocks (1/CU), 9-stage 4-buffer ring ======
// grid (32 jc, 8 kc); block = 288 k-rows x 128 cols; stage = 32 rows (16 KB).
__device__ __forceinline__ void k5_stage(const float* Wk, const float* Wr,
                                         int k0, int t, int jc, float* buf,
                                         int w, int lane) {
    #pragma unroll
    for (int i = 0; i < 4; ++i) {
        int flat = (w * 4 + i) * 1024 + lane * 16;   // byte offset in 16 KB tile
        int row = flat >> 9;                          // 512 B per tile row
        int colb = flat & 511;
        int k = k0 + t * 32 + row;
        const char* g = ((k < DIN + E) ? (const char*)(Wk + (size_t)k * N4)
                                       : (const char*)(Wr + (size_t)(k - DIN - E) * N4))
                        + jc * 512 + colb;
        char* l = (char*)buf + (w * 4 + i) * 1024;    // wave-uniform dest
        __builtin_amdgcn_global_load_lds((const __attribute__((address_space(1))) void*)g,
                                         (__attribute__((address_space(3))) void*)l,
                                         16, 0, 0);
    }
}

__global__ __launch_bounds__(256) void k5_z(const float* __restrict__ xin,
                                            const float* __restrict__ ctx,
                                            const float* __restrict__ h,
                                            const float* __restrict__ Wk,
                                            const float* __restrict__ Wr,
                                            float* __restrict__ zpart) {
    const int jc = blockIdx.x;  // 0..31
    const int kc = blockIdx.y;  // 0..7
    const int tid = threadIdx.x;
    const int k0 = kc * KCH;
    __shared__ float wt[4][4096];    // ring, 64 KB
    __shared__ float xs[KCH][36];    // [k][b] transposed, padded; 41.5 KB
    // ---- stage x transposed (coalesced along k)
    #pragma unroll
    for (int i = 0; i < 36; ++i) {
        int f = i * 256 + tid;       // 9216 = 32 b * 288 k
        int b = f / KCH, kk = f % KCH;
        int k = k0 + kk;
        float v;
        if (k < DIN)          v = xin[b * DIN + k];
        else if (k < DIN + E) v = ctx[b * E + (k - DIN)];
        else                  v = h[b * U + (k - DIN - E)];
        xs[kk][b] = v;
    }
    asm volatile("s_waitcnt vmcnt(0)" ::: "memory");  // x loads drained: vmcnt now counts stages only

    const int w = tid >> 6, lane = tid & 63;
    const int jg = lane & 7;    // 8 col-groups x 4 -> wave covers cols w*32..+31
    const int bg = lane >> 3;   // 8 b-groups x 4  -> all 32 b per wave
    float4 a0{}, a1{}, a2{}, a3{};

    k5_stage(Wk, Wr, k0, 0, jc, wt[0], w, lane);
    k5_stage(Wk, Wr, k0, 1, jc, wt[1], w, lane);
    k5_stage(Wk, Wr, k0, 2, jc, wt[2], w, lane);
    #pragma unroll
    for (int s = 0; s < NST; ++s) {
        if (s + 3 < NST) k5_stage(Wk, Wr, k0, s + 3, jc, wt[(s + 3) & 3], w, lane);
        if (s == 0)           asm volatile("s_waitcnt vmcnt(12) lgkmcnt(0)" ::: "memory");
        else if (s < NST - 3) asm volatile("s_waitcnt vmcnt(12)" ::: "memory");
        else if (s == NST - 3) asm volatile("s_waitcnt vmcnt(8)" ::: "memory");
        else if (s == NST - 2) asm volatile("s_waitcnt vmcnt(4)" ::: "memory");
        else                  asm volatile("s_waitcnt vmcnt(0)" ::: "memory");
        __builtin_amdgcn_s_barrier();
        const float* wb = wt[s & 3];
        #pragma unroll 8
        for (int r = 0; r < 32; ++r) {
            float4 w4 = *(const float4*)(wb + r * 128 + w * 32 + jg * 4);
            float4 x4 = *(const float4*)&xs[s * 32 + r][bg * 4];
            a0.x += x4.x * w4.x; a0.y += x4.x * w4.y; a0.z += x4.x * w4.z; a0.w += x4.x * w4.w;
            a1.x += x4.y * w4.x; a1.y += x4.y * w4.y; a1.z += x4.y * w4.z; a1.w += x4.y * w4.w;
            a2.x += x4.z * w4.x; a2.y += x4.z * w4.y; a2.z += x4.z * w4.z; a2.w += x4.z * w4.w;
            a3.x += x4.w * w4.x; a3.y += x4.w * w4.y; a3.z += x4.w * w4.z; a3.w += x4.w * w4.w;
        }
        __builtin_amdgcn_s_barrier();   // all waves done reading before ring slot is re-staged
    }
    float* zp = zpart + ((size_t)(kc * 32 + bg * 4)) * N4 + jc * 128 + w * 32 + jg * 4;
    *(float4*)(zp + 0 * N4) = a0;
    *(float4*)(zp + 1 * N4) = a1;
    *(float4*)(zp + 2 * N4) = a2;
    *(float4*)(zp + 3 * N4) = a3;
}

// ================= K6: z = sum(8 zparts) + bias -> gates -> outputs =========
__global__ __launch_bounds__(256) void k6_gates(const float* __restrict__ zpart,
                                                const float* __restrict__ bias,
                                                const float* __restrict__ c,
                                                float* __restrict__ out) {
    int idx = blockIdx.x * 256 + threadIdx.x;  // 32768 = b*1024+u
    int b = idx >> 10, u = idx & 1023;
    float zi = bias[u], zf = bias[U + u], zg = bias[2 * U + u], zo = bias[3 * U + u];
    #pragma unroll
    for (int s = 0; s < 8; ++s) {
        const float* zp = zpart + ((size_t)(s * 32 + b)) * N4;
        zi += zp[u]; zf += zp[U + u]; zg += zp[2 * U + u]; zo += zp[3 * U + u];
    }
    float cn = fast_sigmoid(zf) * c[idx] + fast_sigmoid(zi) * fast_tanh(zg);
    float hn = fast_sigmoid(zo) * fast_tanh(cn);
    out[idx] = hn;
    out[32768 + idx] = hn;
    out[65536 + idx] = cn;
}

extern "C" void kernel_launch(void* const* d_in, const int* in_sizes, int n_in,
                              void* d_out, int out_size, void* d_ws, size_t ws_size,
                              hipStream_t stream) {
    const float* inputs = (const float*)d_in[0];
    const float* h      = (const float*)d_in[1];
    const float* c      = (const float*)d_in[2];
    const float* speech = (const float*)d_in[3];
    const float* enc    = (const float*)d_in[4];
    const float* Wa_w   = (const float*)d_in[5];
    const float* Wa_b   = (const float*)d_in[6];
    const float* va_w   = (const float*)d_in[7];
    const float* va_b   = (const float*)d_in[8];
    const float* Wk     = (const float*)d_in[9];
    const float* Wr     = (const float*)d_in[10];
    const float* bias   = (const float*)d_in[11];
    float* out = (float*)d_out;
    float* ws  = (float*)d_ws;

    // big region reused sequentially: qpart (4 MB) -> ctxpart (4 MB) -> zpart (4 MB)
    float* big     = ws;                 // 1048576 floats
    float* qpart   = big;                // 32*32768
    float* ctxpart = big;                // 32*32768
    float* zpart   = big;                // 8*131072
    float* query   = ws + 1048576;       // 32768
    float* context = ws + 1081344;       // 32768
    float* logits  = ws + 1114112;       // 16384
    float* attn    = ws + 1130496;       // 16384  (end ~4.6 MB)

    k1_query<<<dim3(8, 32), 256, 0, stream>>>(h, Wa_w, qpart);
    k1b_qreduce<<<128, 256, 0, stream>>>(qpart, Wa_b, query);
    k2_logits<<<4096, 256, 0, stream>>>(query, enc, va_w, va_b, logits);
    k3_softmax<<<32, 256, 0, stream>>>(logits, attn);
    k4_ctx<<<1024, 256, 0, stream>>>(attn, speech, ctxpart);
    k4b_ctxreduce<<<128, 256, 0, stream>>>(ctxpart, context);
    k5_z<<<dim3(32, 8), 256, 0, stream>>>(inputs, context, h, Wk, Wr, zpart);
    k6_gates<<<128, 256, 0, stream>>>(zpart, bias, c, out);
}

// Round 7
// 224.746 us; speedup vs baseline: 1.0561x; 1.0561x over previous
//
#include <hip/hip_runtime.h>
#include <hip/hip_bf16.h>

#define B 32
#define T 512
#define U 1024
#define E 1024
#define DIN 256
#define N4 4096  // 4*U

__device__ __forceinline__ float fast_tanh(float x) {
    float e = __expf(2.0f * x);
    return 1.0f - 2.0f / (e + 1.0f);
}
__device__ __forceinline__ float fast_sigmoid(float x) {
    return 1.0f / (1.0f + __expf(-x));
}

// ================= K1: qpart[kc][b][u] partials of h @ Wa_w =================
__global__ __launch_bounds__(256) void k1_query(const float* __restrict__ h,
                                                const float* __restrict__ Wa_w,
                                                float* __restrict__ qpart) {
    const int jc = blockIdx.x;   // 0..7
    const int kc = blockIdx.y;   // 0..31
    const int tid = threadIdx.x;
    const int k0 = kc * 32;
    __shared__ float hs[32][36];   // [k][b] transposed, padded
    #pragma unroll
    for (int i = 0; i < 4; ++i) {
        int flat = i * 256 + tid;        // 1024
        int kk = flat & 31, b = flat >> 5;
        hs[kk][b] = h[(size_t)b * U + k0 + kk];
    }
    __syncthreads();
    const int jg = tid & 31;
    const int bg = tid >> 5;             // 0..7 -> batches bg*4..+3
    const int ROWS = U / 4;              // float4 stride per k-row
    const float4* Wp = (const float4*)(Wa_w + (size_t)k0 * U + jc * 128) + jg;
    float4 a0{}, a1{}, a2{}, a3{};
    float4 w0 = Wp[0 * ROWS], w1 = Wp[1 * ROWS], w2 = Wp[2 * ROWS], w3 = Wp[3 * ROWS];
#define K1_FMA(W, R)                                                            \
    {                                                                           \
        float4 x4 = *(const float4*)&hs[(R)][bg * 4];                           \
        a0.x += x4.x * (W).x; a0.y += x4.x * (W).y; a0.z += x4.x * (W).z; a0.w += x4.x * (W).w; \
        a1.x += x4.y * (W).x; a1.y += x4.y * (W).y; a1.z += x4.y * (W).z; a1.w += x4.y * (W).w; \
        a2.x += x4.z * (W).x; a2.y += x4.z * (W).y; a2.z += x4.z * (W).z; a2.w += x4.z * (W).w; \
        a3.x += x4.w * (W).x; a3.y += x4.w * (W).y; a3.z += x4.w * (W).z; a3.w += x4.w * (W).w; \
    }
    #pragma unroll 1
    for (int r = 0; r <= 24; r += 4) {
        float4 n0 = Wp[(r + 4) * ROWS], n1 = Wp[(r + 5) * ROWS];
        float4 n2 = Wp[(r + 6) * ROWS], n3 = Wp[(r + 7) * ROWS];
        K1_FMA(w0, r + 0); K1_FMA(w1, r + 1); K1_FMA(w2, r + 2); K1_FMA(w3, r + 3);
        w0 = n0; w1 = n1; w2 = n2; w3 = n3;
        if (r == 24) break;  // rows 28..31 remain in w0..w3
    }
    K1_FMA(w0, 28); K1_FMA(w1, 29); K1_FMA(w2, 30); K1_FMA(w3, 31);
#undef K1_FMA
    float* q = qpart + ((size_t)(kc * 32 + bg * 4)) * U + jc * 128 + jg * 4;
    *(float4*)(q + 0 * U) = a0;
    *(float4*)(q + 1 * U) = a1;
    *(float4*)(q + 2 * U) = a2;
    *(float4*)(q + 3 * U) = a3;
}

// ================= K1b: query = sum(32 qparts) + Wa_b =================
__global__ __launch_bounds__(256) void k1b_qreduce(const float* __restrict__ qpart,
                                                   const float* __restrict__ Wa_b,
                                                   float* __restrict__ query) {
    int i = blockIdx.x * 256 + threadIdx.x;  // 32768
    const float* p = qpart + i;
    float s = Wa_b[i & 1023];
    #pragma unroll
    for (int g = 0; g < 8; ++g) {
        float b0 = p[(size_t)(4 * g + 0) * 32768];
        float b1 = p[(size_t)(4 * g + 1) * 32768];
        float b2 = p[(size_t)(4 * g + 2) * 32768];
        float b3 = p[(size_t)(4 * g + 3) * 32768];
        s += b0 + b1 + b2 + b3;
    }
    query[i] = s;
}

// ================= K2: logits =================
__global__ __launch_bounds__(256) void k2_logits(const float* __restrict__ query,
                                                 const float* __restrict__ enc,
                                                 const float* __restrict__ va_w,
                                                 const float* __restrict__ va_b,
                                                 float* __restrict__ logits) {
    int gw = blockIdx.x * 4 + (threadIdx.x >> 6);
    int lane = threadIdx.x & 63;
    int b = gw >> 9, t = gw & 511;
    const float4* e4 = (const float4*)(enc + ((size_t)(b * T + t)) * U);
    const float4* q4 = (const float4*)(query + (size_t)b * U);
    const float4* v4 = (const float4*)va_w;
    float4 e[4], q[4], v[4];
    #pragma unroll
    for (int i = 0; i < 4; ++i) {
        int idx = i * 64 + lane;
        e[i] = e4[idx]; q[i] = q4[idx]; v[i] = v4[idx];
    }
    float acc = 0.f;
    #pragma unroll
    for (int i = 0; i < 4; ++i) {
        acc += fast_tanh(e[i].x + q[i].x) * v[i].x;
        acc += fast_tanh(e[i].y + q[i].y) * v[i].y;
        acc += fast_tanh(e[i].z + q[i].z) * v[i].z;
        acc += fast_tanh(e[i].w + q[i].w) * v[i].w;
    }
    #pragma unroll
    for (int off = 32; off > 0; off >>= 1) acc += __shfl_xor(acc, off);
    if (lane == 0) logits[b * T + t] = acc + va_b[0];
}

// ================= K3: softmax =================
__global__ __launch_bounds__(256) void k3_softmax(const float* __restrict__ logits,
                                                  float* __restrict__ attn) {
    int b = blockIdx.x, tid = threadIdx.x, lane = tid & 63, w = tid >> 6;
    float l0 = logits[b * T + tid], l1 = logits[b * T + 256 + tid];
    float m = fmaxf(l0, l1);
    #pragma unroll
    for (int off = 32; off > 0; off >>= 1) m = fmaxf(m, __shfl_xor(m, off));
    __shared__ float sm[4], ss[4];
    if (lane == 0) sm[w] = m;
    __syncthreads();
    float M = fmaxf(fmaxf(sm[0], sm[1]), fmaxf(sm[2], sm[3]));
    float e0 = __expf(l0 - M), e1 = __expf(l1 - M);
    float s = e0 + e1;
    #pragma unroll
    for (int off = 32; off > 0; off >>= 1) s += __shfl_xor(s, off);
    if (lane == 0) ss[w] = s;
    __syncthreads();
    float inv = 1.0f / (ss[0] + ss[1] + ss[2] + ss[3]);
    attn[b * T + tid] = e0 * inv;
    attn[b * T + 256 + tid] = e1 * inv;
}

// ================= K4: ctxpart[slice][b][e] =================
__global__ __launch_bounds__(256) void k4_ctx(const float* __restrict__ attn,
                                              const float* __restrict__ speech,
                                              float* __restrict__ ctxpart) {
    int bid = blockIdx.x;
    int eh = bid & 1, tc = (bid >> 1) & 15, b = bid >> 5;
    int t0 = tc * 32;
    __shared__ float sat[32];
    if (threadIdx.x < 32) sat[threadIdx.x] = attn[b * T + t0 + threadIdx.x];
    __syncthreads();
    int eg = threadIdx.x & 127;
    int ts = threadIdx.x >> 7;           // 0/1 sub-stream
    int e = eh * 512 + eg * 4;
    const int S = E / 4;
    const float4* sp = (const float4*)(speech + ((size_t)(b * T + t0 + ts * 16)) * E + e);
    float4 acc{};
    float4 p0 = sp[0 * S], p1 = sp[1 * S], p2 = sp[2 * S], p3 = sp[3 * S];
    const float* a = &sat[ts * 16];
    #pragma unroll 1
    for (int tt = 0; tt <= 8; tt += 4) {
        float4 n0 = sp[(size_t)(tt + 4) * S], n1 = sp[(size_t)(tt + 5) * S];
        float4 n2 = sp[(size_t)(tt + 6) * S], n3 = sp[(size_t)(tt + 7) * S];
        float c0 = a[tt + 0], c1 = a[tt + 1], c2 = a[tt + 2], c3 = a[tt + 3];
        acc.x += c0 * p0.x; acc.y += c0 * p0.y; acc.z += c0 * p0.z; acc.w += c0 * p0.w;
        acc.x += c1 * p1.x; acc.y += c1 * p1.y; acc.z += c1 * p1.z; acc.w += c1 * p1.w;
        acc.x += c2 * p2.x; acc.y += c2 * p2.y; acc.z += c2 * p2.z; acc.w += c2 * p2.w;
        acc.x += c3 * p3.x; acc.y += c3 * p3.y; acc.z += c3 * p3.z; acc.w += c3 * p3.w;
        p0 = n0; p1 = n1; p2 = n2; p3 = n3;
        if (tt == 8) break;  // rows 12..15 in p0..p3
    }
    {
        float c0 = a[12], c1 = a[13], c2 = a[14], c3 = a[15];
        acc.x += c0 * p0.x; acc.y += c0 * p0.y; acc.z += c0 * p0.z; acc.w += c0 * p0.w;
        acc.x += c1 * p1.x; acc.y += c1 * p1.y; acc.z += c1 * p1.z; acc.w += c1 * p1.w;
        acc.x += c2 * p2.x; acc.y += c2 * p2.y; acc.z += c2 * p2.z; acc.w += c2 * p2.w;
        acc.x += c3 * p3.x; acc.y += c3 * p3.y; acc.z += c3 * p3.z; acc.w += c3 * p3.w;
    }
    int slice = tc * 2 + ts;             // 0..31
    *(float4*)(ctxpart + ((size_t)(slice * 32 + b)) * E + e) = acc;
}

// ================= K4b: context = sum(32 ctxparts) =================
__global__ __launch_bounds__(256) void k4b_ctxreduce(const float* __restrict__ ctxpart,
                                                     float* __restrict__ context) {
    int i = blockIdx.x * 256 + threadIdx.x;  // 32768
    const float* p = ctxpart + i;
    float s = 0.f;
    #pragma unroll
    for (int g = 0; g < 8; ++g) {
        float b0 = p[(size_t)(4 * g + 0) * 32768];
        float b1 = p[(size_t)(4 * g + 1) * 32768];
        float b2 = p[(size_t)(4 * g + 2) * 32768];
        float b3 = p[(size_t)(4 * g + 3) * 32768];
        s += b0 + b1 + b2 + b3;
    }
    context[i] = s;
}

// ================= K5: zpart via global_load_lds double-buffered pipeline ======
// grid (32 jc, 18 kc); block tile = 128 k-rows x 128 cols, 4 sub-tiles of 32 rows.
// Lane map: jg=lane&7 (8 col-quads), bg=lane>>3 (8 b-quads); wave w owns cols w*32..+31.
__device__ __forceinline__ void k5_stage(const char* gbase, int t, float* ldsbuf,
                                         int w, int lane) {
    #pragma unroll
    for (int i = 0; i < 4; ++i) {
        int flat = (w * 4 + i) * 1024 + lane * 16;   // byte offset in 16 KB tile
        int row = flat >> 9;                          // 512 B per tile row
        int colb = flat & 511;
        const char* g = gbase + ((size_t)(t * 32 + row)) * (N4 * 4) + colb;
        char* l = (char*)ldsbuf + (size_t)(w * 4 + i) * 1024;  // wave-uniform dest
        __builtin_amdgcn_global_load_lds((const __attribute__((address_space(1))) void*)g,
                                         (__attribute__((address_space(3))) void*)l,
                                         16, 0, 0);
    }
}

__global__ __launch_bounds__(256) void k5_z(const float* __restrict__ xin,
                                            const float* __restrict__ ctx,
                                            const float* __restrict__ h,
                                            const float* __restrict__ Wk,
                                            const float* __restrict__ Wr,
                                            float* __restrict__ zpart) {
    const int jc = blockIdx.x;  // 0..31
    const int kc = blockIdx.y;  // 0..17
    const int tid = threadIdx.x;
    const int k0 = kc * 128;
    __shared__ float wtile[2][4096];   // 2 x 16 KB
    __shared__ float xs[128][36];      // [k][b], padded rows (144 B, 16B-aligned)
    // stage x (transposed)
    const float* xsrc; int xoff, xld;
    if (k0 < DIN)          { xsrc = xin; xoff = k0;           xld = DIN; }
    else if (k0 < DIN + E) { xsrc = ctx; xoff = k0 - DIN;     xld = E;   }
    else                   { xsrc = h;   xoff = k0 - DIN - E; xld = U;   }
    #pragma unroll
    for (int i = 0; i < 16; ++i) {
        int flat = i * 256 + tid;     // 4096
        int kk = flat & 127, b = flat >> 7;
        xs[kk][b] = xsrc[(size_t)b * xld + xoff + kk];
    }
    const float* Wbase = (k0 < DIN + E) ? (Wk + (size_t)k0 * N4)
                                        : (Wr + (size_t)(k0 - DIN - E) * N4);
    const char* gtile = (const char*)(Wbase + jc * 128);
    const int w = tid >> 6, lane = tid & 63;
    const int jg = lane & 7;    // col quad within wave's 32-col slice
    const int bg = lane >> 3;   // batch quad
    float4 a0{}, a1{}, a2{}, a3{};

    k5_stage(gtile, 0, wtile[0], w, lane);
    #pragma unroll
    for (int s = 0; s < 4; ++s) {
        if (s < 3) k5_stage(gtile, s + 1, wtile[(s + 1) & 1], w, lane);
        if (s == 0)      asm volatile("s_waitcnt vmcnt(4) lgkmcnt(0)" ::: "memory");
        else if (s < 3)  asm volatile("s_waitcnt vmcnt(4)" ::: "memory");
        else             asm volatile("s_waitcnt vmcnt(0)" ::: "memory");
        __builtin_amdgcn_s_barrier();
        const float* wb = wtile[s & 1];
        const int r0 = s * 32;
        #pragma unroll 8
        for (int r = 0; r < 32; ++r) {
            float4 w4 = *(const float4*)(wb + r * 128 + w * 32 + jg * 4);
            float4 x4 = *(const float4*)&xs[r0 + r][bg * 4];
            a0.x += x4.x * w4.x; a0.y += x4.x * w4.y; a0.z += x4.x * w4.z; a0.w += x4.x * w4.w;
            a1.x += x4.y * w4.x; a1.y += x4.y * w4.y; a1.z += x4.y * w4.z; a1.w += x4.y * w4.w;
            a2.x += x4.z * w4.x; a2.y += x4.z * w4.y; a2.z += x4.z * w4.z; a2.w += x4.z * w4.w;
            a3.x += x4.w * w4.x; a3.y += x4.w * w4.y; a3.z += x4.w * w4.z; a3.w += x4.w * w4.w;
        }
        __builtin_amdgcn_s_barrier();
    }
    float* zp = zpart + ((size_t)(kc * 32 + bg * 4)) * N4 + jc * 128 + w * 32 + jg * 4;
    *(float4*)(zp + 0 * N4) = a0;
    *(float4*)(zp + 1 * N4) = a1;
    *(float4*)(zp + 2 * N4) = a2;
    *(float4*)(zp + 3 * N4) = a3;
}

// ================= K6: z = sum(18 zparts) + bias -> gates -> outputs =========
__global__ __launch_bounds__(256) void k6_gates(const float* __restrict__ zpart,
                                                const float* __restrict__ bias,
                                                const float* __restrict__ c,
                                                float* __restrict__ out) {
    int idx = blockIdx.x * 256 + threadIdx.x;  // 32768 = b*1024+u
    int b = idx >> 10, u = idx & 1023;
    float zi = bias[u], zf = bias[U + u], zg = bias[2 * U + u], zo = bias[3 * U + u];
    #pragma unroll
    for (int s = 0; s < 18; ++s) {
        const float* zp = zpart + ((size_t)(s * 32 + b)) * N4;
        zi += zp[u]; zf += zp[U + u]; zg += zp[2 * U + u]; zo += zp[3 * U + u];
    }
    float cn = fast_sigmoid(zf) * c[idx] + fast_sigmoid(zi) * fast_tanh(zg);
    float hn = fast_sigmoid(zo) * fast_tanh(cn);
    out[idx] = hn;
    out[32768 + idx] = hn;
    out[65536 + idx] = cn;
}

extern "C" void kernel_launch(void* const* d_in, const int* in_sizes, int n_in,
                              void* d_out, int out_size, void* d_ws, size_t ws_size,
                              hipStream_t stream) {
    const float* inputs = (const float*)d_in[0];
    const float* h      = (const float*)d_in[1];
    const float* c      = (const float*)d_in[2];
    const float* speech = (const float*)d_in[3];
    const float* enc    = (const float*)d_in[4];
    const float* Wa_w   = (const float*)d_in[5];
    const float* Wa_b   = (const float*)d_in[6];
    const float* va_w   = (const float*)d_in[7];
    const float* va_b   = (const float*)d_in[8];
    const float* Wk     = (const float*)d_in[9];
    const float* Wr     = (const float*)d_in[10];
    const float* bias   = (const float*)d_in[11];
    float* out = (float*)d_out;
    float* ws  = (float*)d_ws;

    // big region reused sequentially: qpart (4 MB) -> ctxpart (4 MB) -> zpart (9.4 MB)
    float* big     = ws;                 // 2359296 floats
    float* qpart   = big;                // 32*32768 = 1048576
    float* ctxpart = big;                // 32*32768 = 1048576
    float* zpart   = big;                // 18*131072 = 2359296
    float* query   = ws + 2359296;       // 32768
    float* context = ws + 2392064;       // 32768
    float* logits  = ws + 2424832;       // 16384
    float* attn    = ws + 2441216;       // 16384  (end ~9.8 MB)

    k1_query<<<dim3(8, 32), 256, 0, stream>>>(h, Wa_w, qpart);
    k1b_qreduce<<<128, 256, 0, stream>>>(qpart, Wa_b, query);
    k2_logits<<<4096, 256, 0, stream>>>(query, enc, va_w, va_b, logits);
    k3_softmax<<<32, 256, 0, stream>>>(logits, attn);
    k4_ctx<<<1024, 256, 0, stream>>>(attn, speech, ctxpart);
    k4b_ctxreduce<<<128, 256, 0, stream>>>(ctxpart, context);
    k5_z<<<dim3(32, 18), 256, 0, stream>>>(inputs, context, h, Wk, Wr, zpart);
    k6_gates<<<128, 256, 0, stream>>>(zpart, bias, c, out);
}